// Round 8
// baseline (373.020 us; speedup 1.0000x reference)
//
#include <hip/hip_runtime.h>

#define T_TOK 8192
#define F_IN  2048
#define F_OUT 2048
#define N_EXP 8
#define NKS   (F_IN / 64)      // 32 K-steps of 64
#define MAXTILES 144
#define RT_TPB 16              // tokens per routing block

typedef __attribute__((ext_vector_type(8))) short    short8;
typedef __attribute__((ext_vector_type(4))) float    f32x4;
typedef __attribute__((ext_vector_type(8))) _Float16 half8;
typedef unsigned short ushort;

#define AS1 __attribute__((address_space(1)))
#define AS3 __attribute__((address_space(3)))
#define GLOAD16(g, l) __builtin_amdgcn_global_load_lds((const AS1 unsigned int*)(g), \
                                                       (AS3 unsigned int*)(l), 16, 0, 0)

__device__ inline ushort f2bf(float f) {   // RNE
    unsigned u = __float_as_uint(f);
    u += 0x7FFFu + ((u >> 16) & 1u);
    return (ushort)(u >> 16);
}

// ---------------- fp32 -> bf16 bulk convert (W) ----------------
__global__ __launch_bounds__(256) void cvt_kernel(const float* __restrict__ in,
                                                  ushort* __restrict__ out, int n8) {
    for (int i = blockIdx.x * 256 + threadIdx.x; i < n8; i += gridDim.x * 256) {
        const float4 a = ((const float4*)in)[i * 2 + 0];
        const float4 b = ((const float4*)in)[i * 2 + 1];
        uint4 v;
        v.x = f2bf(a.x) | ((unsigned)f2bf(a.y) << 16);
        v.y = f2bf(a.z) | ((unsigned)f2bf(a.w) << 16);
        v.z = f2bf(b.x) | ((unsigned)f2bf(b.y) << 16);
        v.w = f2bf(b.z) | ((unsigned)f2bf(b.w) << 16);
        ((uint4*)out)[i] = v;
    }
}

// ---------------- routing + fused x->bf16, block-aggregated atomics ----------------
__device__ inline void top2_store(const float* s, int ti, float sc,
                                  int* sh_ei, float (*sh_cf)[2]) {
    float v0 = -1.f; int i0 = 0;
    #pragma unroll
    for (int e = 0; e < N_EXP; ++e) {
        const float a = fabsf(s[e]);
        if (a > v0) { v0 = a; i0 = e; }
    }
    float v1 = -1.f; int i1 = 0;
    #pragma unroll
    for (int e = 0; e < N_EXP; ++e) {
        const float a = fabsf(s[e]);
        if (e != i0 && a > v1) { v1 = a; i1 = e; }
    }
    const float ex  = expf(v1 - v0);
    const float inv = 1.f / (1.f + ex);
    sh_ei[ti]    = i0 | (i1 << 16);
    sh_cf[ti][0] = sc * inv;
    sh_cf[ti][1] = sc * ex * inv;
}

__global__ __launch_bounds__(256) void route_kernel(
    const float* __restrict__ x, const float* __restrict__ protos,
    const int* __restrict__ scaling, ushort* __restrict__ xb,
    int* __restrict__ counts, int* __restrict__ lists, float* __restrict__ coeffs,
    int* __restrict__ pos)
{
    __shared__ int   sh_ei[RT_TPB];
    __shared__ float sh_cf[RT_TPB][2];
    __shared__ int   sh_base[N_EXP];

    const int wave = threadIdx.x >> 6;
    const int lane = threadIdx.x & 63;
    const float sc = (float)(*scaling);

    for (int pr = 0; pr < 2; ++pr) {
        const int ti0  = wave * 4 + pr * 2;
        const int tok0 = blockIdx.x * RT_TPB + ti0;
        const float* xr0 = x  + (size_t)tok0 * F_IN;
        const float* xr1 = xr0 + F_IN;
        ushort*      xo0 = xb + (size_t)tok0 * F_IN;
        ushort*      xo1 = xo0 + F_IN;

        float s0[N_EXP] = {}, s1[N_EXP] = {};
        for (int c = 0; c < F_IN / 256; ++c) {
            const int off = c * 256 + lane * 4;
            const float4 a = *(const float4*)(xr0 + off);
            const float4 b = *(const float4*)(xr1 + off);
            uint2 ba, bb;
            ba.x = f2bf(a.x) | ((unsigned)f2bf(a.y) << 16);
            ba.y = f2bf(a.z) | ((unsigned)f2bf(a.w) << 16);
            bb.x = f2bf(b.x) | ((unsigned)f2bf(b.y) << 16);
            bb.y = f2bf(b.z) | ((unsigned)f2bf(b.w) << 16);
            *(uint2*)(xo0 + off) = ba;
            *(uint2*)(xo1 + off) = bb;
            #pragma unroll
            for (int e = 0; e < N_EXP; ++e) {
                const float4 pv = *(const float4*)(protos + e * F_IN + off);
                s0[e] += a.x * pv.x + a.y * pv.y + a.z * pv.z + a.w * pv.w;
                s1[e] += b.x * pv.x + b.y * pv.y + b.z * pv.z + b.w * pv.w;
            }
        }
        #pragma unroll
        for (int e = 0; e < N_EXP; ++e) {
            float v0 = s0[e], v1 = s1[e];
            #pragma unroll
            for (int off = 32; off; off >>= 1) {
                v0 += __shfl_down(v0, off, 64);
                v1 += __shfl_down(v1, off, 64);
            }
            s0[e] = v0; s1[e] = v1;
        }
        if (lane == 0) {
            top2_store(s0, ti0,     sc, sh_ei, sh_cf);
            top2_store(s1, ti0 + 1, sc, sh_ei, sh_cf);
        }
    }
    __syncthreads();

    if (threadIdx.x < 64) {
        const int  p      = threadIdx.x;
        const bool active = p < RT_TPB * 2;
        const int  ti = p >> 1, j = p & 1;
        const int  e  = active ? ((sh_ei[ti] >> (j * 16)) & 0xffff) : 0xff;
        int rank = 0;
        #pragma unroll
        for (int ee = 0; ee < N_EXP; ++ee) {
            const unsigned long long m = __ballot(active && (e == ee));
            if (e == ee)
                rank = __popcll(m & ((1ull << p) - 1ull));
            if (p == ee && m != 0ull)
                sh_base[ee] = atomicAdd(&counts[ee], (int)__popcll(m));
        }
        if (active) {
            const int position = sh_base[e] + rank;
            const int gidx  = e * T_TOK + position;
            const int token = blockIdx.x * RT_TPB + ti;
            lists [gidx] = token;
            coeffs[gidx] = sh_cf[ti][j];
            pos[token * 2 + j] = gidx;
        }
    }
}

// ---------------- plan: prefix bases + flat tile descriptors ----------------
__global__ void plan_kernel(const int* __restrict__ counts, int* __restrict__ pbase,
                            int* __restrict__ ntiles, int* __restrict__ desc) {
    if (threadIdx.x == 0) {
        int pb = 0, t = 0;
        for (int e = 0; e < N_EXP; ++e) {
            pbase[e] = pb;
            const int ne = counts[e];
            const int nt = (ne + 127) >> 7;
            for (int i = 0; i < nt; ++i) desc[t++] = (e << 8) | i;
            pb += ne;
        }
        *ntiles = t;
    }
}

// ---- grouped bf16 GEMM, 128x256, BK=64, dbuf LDS + counted prefetch, 8 waves ----
__global__ __launch_bounds__(512, 1) void gemm_kernel(
    const ushort* __restrict__ xb, const ushort* __restrict__ Wb,
    const int* __restrict__ counts, const int* __restrict__ lists,
    const int* __restrict__ pbase, const int* __restrict__ ntiles,
    const int* __restrict__ desc, _Float16* __restrict__ delta)
{
    // XCD-bijective map over (tile-major, o0-minor); nwg = 1152, % 8 == 0.
    const int hw = blockIdx.x;
    const int l  = (hw & 7) * MAXTILES + (hw >> 3);
    const int ti = l >> 3;
    const int oi = l & 7;
    if (ti >= *ntiles) return;

    const int d     = desc[ti];
    const int e     = d >> 8;
    const int tile  = d & 255;
    const int n_e   = counts[e];
    const int tbase = tile << 7;
    const int o0    = oi * 256;
    const int prow0 = pbase[e] + tbase;

    __shared__ __align__(16) ushort Ald[2][128 * 64];   // 2 x 16 KiB
    __shared__ __align__(16) ushort Bld[2][256 * 64];   // 2 x 32 KiB

    const int tid  = threadIdx.x;
    const int lane = tid & 63;
    const int wid  = tid >> 6;              // 0..7
    const int wr   = wid >> 2;              // 0..1  (M)
    const int wc   = wid & 3;               // 0..3  (N)

    // ---- staging: per-lane pre-swizzled global src, linear LDS dest ----
    const int ksrc = ((lane & 7) ^ (lane >> 3)) * 8;
    const ushort* srcA[2];
    #pragma unroll
    for (int g = 0; g < 2; ++g) {
        const int row  = g * 64 + wid * 8 + (lane >> 3);
        const int slot = min(tbase + row, n_e - 1);
        srcA[g] = xb + (size_t)lists[e * T_TOK + slot] * F_IN + ksrc;
    }
    const ushort* srcB0 = Wb + ((size_t)(e * F_OUT + o0 + wid * 8 + (lane >> 3))) * F_IN + ksrc;

    #define STAGE(BUF, KT) do { const size_t _k = (size_t)(KT) * 64;             \
        ushort* _a = &Ald[BUF][0]; ushort* _b = &Bld[BUF][0];                    \
        GLOAD16(srcA[0] + _k, _a + (wid * 8) * 64);                              \
        GLOAD16(srcA[1] + _k, _a + (64 + wid * 8) * 64);                         \
        _Pragma("unroll") for (int g = 0; g < 4; ++g)                            \
            GLOAD16(srcB0 + (size_t)g * 64 * F_IN + _k, _b + (g * 64 + wid * 8) * 64); \
    } while (0)

    // ---- fragment read bases (same XOR on read side) ----
    const int octx8 = ((lane >> 4) ^ (lane & 7)) * 8;
    const int ai    = (wr * 64 + (lane & 15)) * 64 + octx8;
    const int bi    = (wc * 64 + (lane & 15)) * 64 + octx8;

    f32x4 acc[4][4] = {};

    STAGE(0, 0);
    __syncthreads();                        // drains vmcnt(0): buf0 ready

    for (int ks = 0; ks < NKS; ++ks) {
        const int cur = ks & 1;
        if (ks + 1 < NKS) STAGE(cur ^ 1, ks + 1);   // prefetch overlaps MFMA below

        const ushort* Ab = &Ald[cur][0];
        const ushort* Bb = &Bld[cur][0];
        short8 a[4][2], b[4][2];
        #pragma unroll
        for (int m = 0; m < 4; ++m) {
            a[m][0] = *(const short8*)(Ab + (ai + m * 1024));
            a[m][1] = *(const short8*)(Ab + ((ai + m * 1024) ^ 32));
        }
        #pragma unroll
        for (int n = 0; n < 4; ++n) {
            b[n][0] = *(const short8*)(Bb + (bi + n * 1024));
            b[n][1] = *(const short8*)(Bb + ((bi + n * 1024) ^ 32));
        }
        #pragma unroll
        for (int kk = 0; kk < 2; ++kk)
            #pragma unroll
            for (int m = 0; m < 4; ++m)
                #pragma unroll
                for (int n = 0; n < 4; ++n)
                    acc[m][n] = __builtin_amdgcn_mfma_f32_16x16x32_bf16(
                        a[m][kk], b[n][kk], acc[m][n], 0, 0, 0);

        __syncthreads();                    // one barrier/step; drains prefetch vmcnt
    }

    // ---- epilogue: single-writer fp16 delta rows ----
    const int rl = (lane >> 4) * 4;
    const int cl = lane & 15;
    #pragma unroll
    for (int m = 0; m < 4; ++m)
        #pragma unroll
        for (int rr = 0; rr < 4; ++rr) {
            const int srow = wr * 64 + m * 16 + rl + rr;
            if (tbase + srow < n_e) {
                _Float16* drow = delta + (size_t)(prow0 + srow) * F_OUT + o0 + wc * 64 + cl;
                #pragma unroll
                for (int n = 0; n < 4; ++n)
                    drow[n * 16] = (_Float16)acc[m][n][rr];
            }
        }
}

// ---------------- combine: out[tok] = cf0*delta[p0] + cf1*delta[p1] ----------------
__global__ __launch_bounds__(256) void combine_kernel(
    const _Float16* __restrict__ delta, const int* __restrict__ pos,
    const float* __restrict__ coeffs, const int* __restrict__ pbase,
    float* __restrict__ out)
{
    const int tok = blockIdx.x;
    const int id0 = pos[tok * 2 + 0];
    const int id1 = pos[tok * 2 + 1];
    const float cf0 = coeffs[id0];
    const float cf1 = coeffs[id1];
    const int r0 = pbase[id0 >> 13] + (id0 & (T_TOK - 1));
    const int r1 = pbase[id1 >> 13] + (id1 & (T_TOK - 1));
    const int c  = threadIdx.x * 8;

    const half8 a = *(const half8*)(delta + (size_t)r0 * F_OUT + c);
    const half8 b = *(const half8*)(delta + (size_t)r1 * F_OUT + c);
    float4 o0, o1;
    o0.x = cf0 * (float)a[0] + cf1 * (float)b[0];
    o0.y = cf0 * (float)a[1] + cf1 * (float)b[1];
    o0.z = cf0 * (float)a[2] + cf1 * (float)b[2];
    o0.w = cf0 * (float)a[3] + cf1 * (float)b[3];
    o1.x = cf0 * (float)a[4] + cf1 * (float)b[4];
    o1.y = cf0 * (float)a[5] + cf1 * (float)b[5];
    o1.z = cf0 * (float)a[6] + cf1 * (float)b[6];
    o1.w = cf0 * (float)a[7] + cf1 * (float)b[7];
    float* op = out + (size_t)tok * F_OUT + c;
    *(float4*)(op)     = o0;
    *(float4*)(op + 4) = o1;
}

extern "C" void kernel_launch(void* const* d_in, const int* in_sizes, int n_in,
                              void* d_out, int out_size, void* d_ws, size_t ws_size,
                              hipStream_t stream) {
    const float* x      = (const float*)d_in[0];
    const float* protos = (const float*)d_in[1];
    const float* W      = (const float*)d_in[2];
    const int*   scal   = (const int*)d_in[3];
    float* out = (float*)d_out;

    char* ws = (char*)d_ws;
    int*      counts = (int*)(ws + 0);
    int*      pbase  = (int*)(ws + 64);
    int*      ntiles = (int*)(ws + 128);
    int*      desc   = (int*)(ws + 256);
    int*      pos    = (int*)(ws + 65536);
    int*      lists  = (int*)(ws + 262144);
    float*    coeffs = (float*)(ws + 524288);
    ushort*   xb     = (ushort*)(ws + (1ull << 20));
    ushort*   Wb     = (ushort*)(ws + (36ull << 20));
    _Float16* delta  = (_Float16*)(ws + (104ull << 20));

    hipMemsetAsync(counts, 0, N_EXP * sizeof(int), stream);

    cvt_kernel<<<2048, 256, 0, stream>>>(W, Wb, N_EXP * F_OUT * F_IN / 8);
    route_kernel<<<T_TOK / RT_TPB, 256, 0, stream>>>(x, protos, scal, xb, counts, lists, coeffs, pos);
    plan_kernel<<<1, 64, 0, stream>>>(counts, pbase, ntiles, desc);

    gemm_kernel<<<MAXTILES * 8, 512, 0, stream>>>(xb, Wb, counts, lists, pbase, ntiles, desc, delta);

    combine_kernel<<<T_TOK, 256, 0, stream>>>(delta, pos, coeffs, pbase, out);
}

// Round 9
// 320.258 us; speedup vs baseline: 1.1647x; 1.1647x over previous
//
#include <hip/hip_runtime.h>

#define T_TOK 8192
#define F_IN  2048
#define F_OUT 2048
#define N_EXP 8
#define NKS   (F_IN / 64)      // 32 K-steps of 64
#define MAXTILES 144
#define RT_TPB 16              // tokens per routing block

typedef __attribute__((ext_vector_type(8))) short    short8;
typedef __attribute__((ext_vector_type(4))) float    f32x4;
typedef __attribute__((ext_vector_type(8))) _Float16 half8;
typedef unsigned short ushort;

#define AS1 __attribute__((address_space(1)))
#define AS3 __attribute__((address_space(3)))
#define GLOAD16(g, l) __builtin_amdgcn_global_load_lds((const AS1 unsigned int*)(g), \
                                                       (AS3 unsigned int*)(l), 16, 0, 0)

__device__ inline ushort f2bf(float f) {   // RNE
    unsigned u = __float_as_uint(f);
    u += 0x7FFFu + ((u >> 16) & 1u);
    return (ushort)(u >> 16);
}

// ---------------- fp32 -> bf16 bulk convert (W) ----------------
__global__ __launch_bounds__(256) void cvt_kernel(const float* __restrict__ in,
                                                  ushort* __restrict__ out, int n8) {
    for (int i = blockIdx.x * 256 + threadIdx.x; i < n8; i += gridDim.x * 256) {
        const float4 a = ((const float4*)in)[i * 2 + 0];
        const float4 b = ((const float4*)in)[i * 2 + 1];
        uint4 v;
        v.x = f2bf(a.x) | ((unsigned)f2bf(a.y) << 16);
        v.y = f2bf(a.z) | ((unsigned)f2bf(a.w) << 16);
        v.z = f2bf(b.x) | ((unsigned)f2bf(b.y) << 16);
        v.w = f2bf(b.z) | ((unsigned)f2bf(b.w) << 16);
        ((uint4*)out)[i] = v;
    }
}

// ---------------- routing + fused x->bf16, block-aggregated atomics ----------------
__device__ inline void top2_store(const float* s, int ti, float sc,
                                  int* sh_ei, float (*sh_cf)[2]) {
    float v0 = -1.f; int i0 = 0;
    #pragma unroll
    for (int e = 0; e < N_EXP; ++e) {
        const float a = fabsf(s[e]);
        if (a > v0) { v0 = a; i0 = e; }
    }
    float v1 = -1.f; int i1 = 0;
    #pragma unroll
    for (int e = 0; e < N_EXP; ++e) {
        const float a = fabsf(s[e]);
        if (e != i0 && a > v1) { v1 = a; i1 = e; }
    }
    const float ex  = expf(v1 - v0);
    const float inv = 1.f / (1.f + ex);
    sh_ei[ti]    = i0 | (i1 << 16);
    sh_cf[ti][0] = sc * inv;
    sh_cf[ti][1] = sc * ex * inv;
}

__global__ __launch_bounds__(256) void route_kernel(
    const float* __restrict__ x, const float* __restrict__ protos,
    const int* __restrict__ scaling, ushort* __restrict__ xb,
    int* __restrict__ counts, int* __restrict__ lists, float* __restrict__ coeffs,
    int* __restrict__ pos)
{
    __shared__ int   sh_ei[RT_TPB];
    __shared__ float sh_cf[RT_TPB][2];
    __shared__ int   sh_base[N_EXP];

    const int wave = threadIdx.x >> 6;
    const int lane = threadIdx.x & 63;
    const float sc = (float)(*scaling);

    for (int pr = 0; pr < 2; ++pr) {
        const int ti0  = wave * 4 + pr * 2;
        const int tok0 = blockIdx.x * RT_TPB + ti0;
        const float* xr0 = x  + (size_t)tok0 * F_IN;
        const float* xr1 = xr0 + F_IN;
        ushort*      xo0 = xb + (size_t)tok0 * F_IN;
        ushort*      xo1 = xo0 + F_IN;

        float s0[N_EXP] = {}, s1[N_EXP] = {};
        for (int c = 0; c < F_IN / 256; ++c) {
            const int off = c * 256 + lane * 4;
            const float4 a = *(const float4*)(xr0 + off);
            const float4 b = *(const float4*)(xr1 + off);
            uint2 ba, bb;
            ba.x = f2bf(a.x) | ((unsigned)f2bf(a.y) << 16);
            ba.y = f2bf(a.z) | ((unsigned)f2bf(a.w) << 16);
            bb.x = f2bf(b.x) | ((unsigned)f2bf(b.y) << 16);
            bb.y = f2bf(b.z) | ((unsigned)f2bf(b.w) << 16);
            *(uint2*)(xo0 + off) = ba;
            *(uint2*)(xo1 + off) = bb;
            #pragma unroll
            for (int e = 0; e < N_EXP; ++e) {
                const float4 pv = *(const float4*)(protos + e * F_IN + off);
                s0[e] += a.x * pv.x + a.y * pv.y + a.z * pv.z + a.w * pv.w;
                s1[e] += b.x * pv.x + b.y * pv.y + b.z * pv.z + b.w * pv.w;
            }
        }
        #pragma unroll
        for (int e = 0; e < N_EXP; ++e) {
            float v0 = s0[e], v1 = s1[e];
            #pragma unroll
            for (int off = 32; off; off >>= 1) {
                v0 += __shfl_down(v0, off, 64);
                v1 += __shfl_down(v1, off, 64);
            }
            s0[e] = v0; s1[e] = v1;
        }
        if (lane == 0) {
            top2_store(s0, ti0,     sc, sh_ei, sh_cf);
            top2_store(s1, ti0 + 1, sc, sh_ei, sh_cf);
        }
    }
    __syncthreads();

    if (threadIdx.x < 64) {
        const int  p      = threadIdx.x;
        const bool active = p < RT_TPB * 2;
        const int  ti = p >> 1, j = p & 1;
        const int  e  = active ? ((sh_ei[ti] >> (j * 16)) & 0xffff) : 0xff;
        int rank = 0;
        #pragma unroll
        for (int ee = 0; ee < N_EXP; ++ee) {
            const unsigned long long m = __ballot(active && (e == ee));
            if (e == ee)
                rank = __popcll(m & ((1ull << p) - 1ull));
            if (p == ee && m != 0ull)
                sh_base[ee] = atomicAdd(&counts[ee], (int)__popcll(m));
        }
        if (active) {
            const int position = sh_base[e] + rank;
            const int gidx  = e * T_TOK + position;
            const int token = blockIdx.x * RT_TPB + ti;
            lists [gidx] = token;
            coeffs[gidx] = sh_cf[ti][j];
            pos[token * 2 + j] = gidx;
        }
    }
}

// ---------------- plan: prefix bases + flat tile descriptors ----------------
__global__ void plan_kernel(const int* __restrict__ counts, int* __restrict__ pbase,
                            int* __restrict__ ntiles, int* __restrict__ desc) {
    if (threadIdx.x == 0) {
        int pb = 0, t = 0;
        for (int e = 0; e < N_EXP; ++e) {
            pbase[e] = pb;
            const int ne = counts[e];
            const int nt = (ne + 127) >> 7;
            for (int i = 0; i < nt; ++i) desc[t++] = (e << 8) | i;
            pb += ne;
        }
        *ntiles = t;
    }
}

// ---- grouped bf16 GEMM, 128x128, BK=64, dbuf + prefetch-before-compute, 4 waves ----
__global__ __launch_bounds__(256, 2) void gemm_kernel(
    const ushort* __restrict__ xb, const ushort* __restrict__ Wb,
    const int* __restrict__ counts, const int* __restrict__ lists,
    const int* __restrict__ pbase, const int* __restrict__ ntiles,
    const int* __restrict__ desc, _Float16* __restrict__ delta)
{
    // XCD-bijective map over (tile-major, o0-minor); nwg = 144*16 = 2304, % 8 == 0.
    const int hw = blockIdx.x;
    const int l  = (hw & 7) * (MAXTILES * 2) + (hw >> 3);
    const int ti = l >> 4;
    const int oi = l & 15;
    if (ti >= *ntiles) return;

    const int d     = desc[ti];
    const int e     = d >> 8;
    const int tile  = d & 255;
    const int n_e   = counts[e];
    const int tbase = tile << 7;
    const int o0    = oi * 128;
    const int prow0 = pbase[e] + tbase;

    __shared__ __align__(16) ushort Ald[2][128 * 64];   // 2 x 16 KiB
    __shared__ __align__(16) ushort Bld[2][128 * 64];   // 2 x 16 KiB  (64 KB total)

    const int tid  = threadIdx.x;
    const int lane = tid & 63;
    const int wid  = tid >> 6;              // 0..3
    const int wr   = wid >> 1, wc = wid & 1;

    // ---- staging: per-lane pre-swizzled global src, linear LDS dest ----
    const int ksrc = ((lane & 7) ^ (lane >> 3)) * 8;
    const ushort* srcA[4];
    #pragma unroll
    for (int g = 0; g < 4; ++g) {
        const int row  = g * 32 + wid * 8 + (lane >> 3);
        const int slot = min(tbase + row, n_e - 1);
        srcA[g] = xb + (size_t)lists[e * T_TOK + slot] * F_IN + ksrc;
    }
    const ushort* srcB0 = Wb + ((size_t)(e * F_OUT + o0 + wid * 8 + (lane >> 3))) * F_IN + ksrc;

    #define STAGE(BUF, KT) do { const size_t _k = (size_t)(KT) * 64;                   \
        ushort* _a = &Ald[BUF][0]; ushort* _b = &Bld[BUF][0];                          \
        _Pragma("unroll") for (int g = 0; g < 4; ++g) {                                \
            GLOAD16(srcA[g] + _k, _a + (g * 32 + wid * 8) * 64);                       \
            GLOAD16(srcB0 + (size_t)g * 32 * F_IN + _k, _b + (g * 32 + wid * 8) * 64); \
        } } while (0)

    // ---- fragment read bases (same XOR on read side) ----
    const int octx8 = ((lane >> 4) ^ (lane & 7)) * 8;
    const int ai    = (wr * 64 + (lane & 15)) * 64 + octx8;
    const int bi    = (wc * 64 + (lane & 15)) * 64 + octx8;

    f32x4 acc[4][4] = {};

    STAGE(0, 0);
    __syncthreads();                        // drains vmcnt(0): buf0 ready

    for (int ks = 0; ks < NKS; ++ks) {
        const int cur = ks & 1;
        if (ks + 1 < NKS) STAGE(cur ^ 1, ks + 1);   // in flight across the compute below

        const ushort* Ab = &Ald[cur][0];
        const ushort* Bb = &Bld[cur][0];
        short8 a[4][2], b[4][2];
        #pragma unroll
        for (int m = 0; m < 4; ++m) {
            a[m][0] = *(const short8*)(Ab + (ai + m * 1024));
            a[m][1] = *(const short8*)(Ab + ((ai + m * 1024) ^ 32));
        }
        #pragma unroll
        for (int n = 0; n < 4; ++n) {
            b[n][0] = *(const short8*)(Bb + (bi + n * 1024));
            b[n][1] = *(const short8*)(Bb + ((bi + n * 1024) ^ 32));
        }
        #pragma unroll
        for (int kk = 0; kk < 2; ++kk)
            #pragma unroll
            for (int m = 0; m < 4; ++m)
                #pragma unroll
                for (int n = 0; n < 4; ++n)
                    acc[m][n] = __builtin_amdgcn_mfma_f32_16x16x32_bf16(
                        a[m][kk], b[n][kk], acc[m][n], 0, 0, 0);

        __syncthreads();                    // one barrier/step; drains prefetch
    }

    // ---- epilogue: single-writer fp16 delta rows ----
    const int rl = (lane >> 4) * 4;
    const int cl = lane & 15;
    #pragma unroll
    for (int m = 0; m < 4; ++m)
        #pragma unroll
        for (int rr = 0; rr < 4; ++rr) {
            const int srow = wr * 64 + m * 16 + rl + rr;
            if (tbase + srow < n_e) {
                _Float16* drow = delta + (size_t)(prow0 + srow) * F_OUT + o0 + wc * 64 + cl;
                #pragma unroll
                for (int n = 0; n < 4; ++n)
                    drow[n * 16] = (_Float16)acc[m][n][rr];
            }
        }
}

// ---------------- combine: out[tok] = cf0*delta[p0] + cf1*delta[p1] ----------------
__global__ __launch_bounds__(256) void combine_kernel(
    const _Float16* __restrict__ delta, const int* __restrict__ pos,
    const float* __restrict__ coeffs, const int* __restrict__ pbase,
    float* __restrict__ out)
{
    const int tok = blockIdx.x;
    const int id0 = pos[tok * 2 + 0];
    const int id1 = pos[tok * 2 + 1];
    const float cf0 = coeffs[id0];
    const float cf1 = coeffs[id1];
    const int r0 = pbase[id0 >> 13] + (id0 & (T_TOK - 1));
    const int r1 = pbase[id1 >> 13] + (id1 & (T_TOK - 1));
    const int c  = threadIdx.x * 8;

    const half8 a = *(const half8*)(delta + (size_t)r0 * F_OUT + c);
    const half8 b = *(const half8*)(delta + (size_t)r1 * F_OUT + c);
    float4 o0, o1;
    o0.x = cf0 * (float)a[0] + cf1 * (float)b[0];
    o0.y = cf0 * (float)a[1] + cf1 * (float)b[1];
    o0.z = cf0 * (float)a[2] + cf1 * (float)b[2];
    o0.w = cf0 * (float)a[3] + cf1 * (float)b[3];
    o1.x = cf0 * (float)a[4] + cf1 * (float)b[4];
    o1.y = cf0 * (float)a[5] + cf1 * (float)b[5];
    o1.z = cf0 * (float)a[6] + cf1 * (float)b[6];
    o1.w = cf0 * (float)a[7] + cf1 * (float)b[7];
    float* op = out + (size_t)tok * F_OUT + c;
    *(float4*)(op)     = o0;
    *(float4*)(op + 4) = o1;
}

extern "C" void kernel_launch(void* const* d_in, const int* in_sizes, int n_in,
                              void* d_out, int out_size, void* d_ws, size_t ws_size,
                              hipStream_t stream) {
    const float* x      = (const float*)d_in[0];
    const float* protos = (const float*)d_in[1];
    const float* W      = (const float*)d_in[2];
    const int*   scal   = (const int*)d_in[3];
    float* out = (float*)d_out;

    char* ws = (char*)d_ws;
    int*      counts = (int*)(ws + 0);
    int*      pbase  = (int*)(ws + 64);
    int*      ntiles = (int*)(ws + 128);
    int*      desc   = (int*)(ws + 256);
    int*      pos    = (int*)(ws + 65536);
    int*      lists  = (int*)(ws + 262144);
    float*    coeffs = (float*)(ws + 524288);
    ushort*   xb     = (ushort*)(ws + (1ull << 20));
    ushort*   Wb     = (ushort*)(ws + (36ull << 20));
    _Float16* delta  = (_Float16*)(ws + (104ull << 20));

    hipMemsetAsync(counts, 0, N_EXP * sizeof(int), stream);

    cvt_kernel<<<2048, 256, 0, stream>>>(W, Wb, N_EXP * F_OUT * F_IN / 8);
    route_kernel<<<T_TOK / RT_TPB, 256, 0, stream>>>(x, protos, scal, xb, counts, lists, coeffs, pos);
    plan_kernel<<<1, 64, 0, stream>>>(counts, pbase, ntiles, desc);

    gemm_kernel<<<MAXTILES * 16, 256, 0, stream>>>(xb, Wb, counts, lists, pbase, ntiles, desc, delta);

    combine_kernel<<<T_TOK, 256, 0, stream>>>(delta, pos, coeffs, pbase, out);
}

// Round 10
// 293.318 us; speedup vs baseline: 1.2717x; 1.0918x over previous
//
#include <hip/hip_runtime.h>

#define T_TOK 8192
#define F_IN  2048
#define F_OUT 2048
#define N_EXP 8
#define NKS   (F_IN / 64)      // 32 K-steps of 64
#define MAXTILES 144
#define RT_TPB 16              // tokens per routing block
#define ROUTE_BLOCKS (T_TOK / RT_TPB)   // 512
#define CVT_BLOCKS   2048

typedef __attribute__((ext_vector_type(8))) short    short8;
typedef __attribute__((ext_vector_type(4))) float    f32x4;
typedef __attribute__((ext_vector_type(8))) _Float16 half8;
typedef unsigned short ushort;

#define AS1 __attribute__((address_space(1)))
#define AS3 __attribute__((address_space(3)))
#define GLOAD16(g, l) __builtin_amdgcn_global_load_lds((const AS1 unsigned int*)(g), \
                                                       (AS3 unsigned int*)(l), 16, 0, 0)

__device__ inline ushort f2bf(float f) {   // RNE
    unsigned u = __float_as_uint(f);
    u += 0x7FFFu + ((u >> 16) & 1u);
    return (ushort)(u >> 16);
}

__device__ inline void top2_store(const float* s, int ti, float sc,
                                  int* sh_ei, float (*sh_cf)[2]) {
    float v0 = -1.f; int i0 = 0;
    #pragma unroll
    for (int e = 0; e < N_EXP; ++e) {
        const float a = fabsf(s[e]);
        if (a > v0) { v0 = a; i0 = e; }
    }
    float v1 = -1.f; int i1 = 0;
    #pragma unroll
    for (int e = 0; e < N_EXP; ++e) {
        const float a = fabsf(s[e]);
        if (e != i0 && a > v1) { v1 = a; i1 = e; }
    }
    const float ex  = expf(v1 - v0);
    const float inv = 1.f / (1.f + ex);
    sh_ei[ti]    = i0 | (i1 << 16);
    sh_cf[ti][0] = sc * inv;
    sh_cf[ti][1] = sc * ex * inv;
}

// ---- fused: blocks [0,512) do routing + x->bf16; blocks [512,2560) do W->bf16 ----
__global__ __launch_bounds__(256) void route_cvt_kernel(
    const float* __restrict__ x, const float* __restrict__ protos,
    const int* __restrict__ scaling, ushort* __restrict__ xb,
    int* __restrict__ counts, int* __restrict__ lists, float* __restrict__ coeffs,
    int* __restrict__ pos, const float* __restrict__ W, ushort* __restrict__ Wb)
{
    __shared__ int   sh_ei[RT_TPB];
    __shared__ float sh_cf[RT_TPB][2];
    __shared__ int   sh_base[N_EXP];

    if (blockIdx.x >= ROUTE_BLOCKS) {
        // -------- W fp32 -> bf16 (grid-stride over 2048 blocks) --------
        const int n8 = N_EXP * F_OUT * F_IN / 8;
        for (int i = (blockIdx.x - ROUTE_BLOCKS) * 256 + threadIdx.x; i < n8;
             i += CVT_BLOCKS * 256) {
            const float4 a = ((const float4*)W)[i * 2 + 0];
            const float4 b = ((const float4*)W)[i * 2 + 1];
            uint4 v;
            v.x = f2bf(a.x) | ((unsigned)f2bf(a.y) << 16);
            v.y = f2bf(a.z) | ((unsigned)f2bf(a.w) << 16);
            v.z = f2bf(b.x) | ((unsigned)f2bf(b.y) << 16);
            v.w = f2bf(b.z) | ((unsigned)f2bf(b.w) << 16);
            ((uint4*)Wb)[i] = v;
        }
        return;
    }

    // -------- routing (16 tokens/block) + fused x->bf16 --------
    const int wave = threadIdx.x >> 6;
    const int lane = threadIdx.x & 63;
    const float sc = (float)(*scaling);

    for (int pr = 0; pr < 2; ++pr) {
        const int ti0  = wave * 4 + pr * 2;
        const int tok0 = blockIdx.x * RT_TPB + ti0;
        const float* xr0 = x  + (size_t)tok0 * F_IN;
        const float* xr1 = xr0 + F_IN;
        ushort*      xo0 = xb + (size_t)tok0 * F_IN;
        ushort*      xo1 = xo0 + F_IN;

        float s0[N_EXP] = {}, s1[N_EXP] = {};
        for (int c = 0; c < F_IN / 256; ++c) {
            const int off = c * 256 + lane * 4;
            const float4 a = *(const float4*)(xr0 + off);
            const float4 b = *(const float4*)(xr1 + off);
            uint2 ba, bb;
            ba.x = f2bf(a.x) | ((unsigned)f2bf(a.y) << 16);
            ba.y = f2bf(a.z) | ((unsigned)f2bf(a.w) << 16);
            bb.x = f2bf(b.x) | ((unsigned)f2bf(b.y) << 16);
            bb.y = f2bf(b.z) | ((unsigned)f2bf(b.w) << 16);
            *(uint2*)(xo0 + off) = ba;
            *(uint2*)(xo1 + off) = bb;
            #pragma unroll
            for (int e = 0; e < N_EXP; ++e) {
                const float4 pv = *(const float4*)(protos + e * F_IN + off);
                s0[e] += a.x * pv.x + a.y * pv.y + a.z * pv.z + a.w * pv.w;
                s1[e] += b.x * pv.x + b.y * pv.y + b.z * pv.z + b.w * pv.w;
            }
        }
        #pragma unroll
        for (int e = 0; e < N_EXP; ++e) {
            float v0 = s0[e], v1 = s1[e];
            #pragma unroll
            for (int off = 32; off; off >>= 1) {
                v0 += __shfl_down(v0, off, 64);
                v1 += __shfl_down(v1, off, 64);
            }
            s0[e] = v0; s1[e] = v1;
        }
        if (lane == 0) {
            top2_store(s0, ti0,     sc, sh_ei, sh_cf);
            top2_store(s1, ti0 + 1, sc, sh_ei, sh_cf);
        }
    }
    __syncthreads();

    if (threadIdx.x < 64) {
        const int  p      = threadIdx.x;
        const bool active = p < RT_TPB * 2;
        const int  ti = p >> 1, j = p & 1;
        const int  e  = active ? ((sh_ei[ti] >> (j * 16)) & 0xffff) : 0xff;
        int rank = 0;
        #pragma unroll
        for (int ee = 0; ee < N_EXP; ++ee) {
            const unsigned long long m = __ballot(active && (e == ee));
            if (e == ee)
                rank = __popcll(m & ((1ull << p) - 1ull));
            if (p == ee && m != 0ull)
                sh_base[ee] = atomicAdd(&counts[ee], (int)__popcll(m));
        }
        if (active) {
            const int position = sh_base[e] + rank;
            const int gidx  = e * T_TOK + position;
            const int token = blockIdx.x * RT_TPB + ti;
            lists [gidx] = token;
            coeffs[gidx] = sh_cf[ti][j];
            pos[token * 2 + j] = gidx;
        }
    }
}

// ---------------- plan: prefix bases + flat tile descriptors ----------------
__global__ void plan_kernel(const int* __restrict__ counts, int* __restrict__ pbase,
                            int* __restrict__ ntiles, int* __restrict__ desc) {
    if (threadIdx.x == 0) {
        int pb = 0, t = 0;
        for (int e = 0; e < N_EXP; ++e) {
            pbase[e] = pb;
            const int ne = counts[e];
            const int nt = (ne + 127) >> 7;
            for (int i = 0; i < nt; ++i) desc[t++] = (e << 8) | i;
            pb += ne;
        }
        *ntiles = t;
    }
}

// ---- grouped bf16 GEMM, 128x256, BK=64, 2-phase, swizzled LDS, XCD-swizzled grid ----
// (round-7 configuration: measured 177 us, MfmaUtil 32.6, FETCH 156 MB, conflicts 0)
__global__ __launch_bounds__(256, 2) void gemm_kernel(
    const ushort* __restrict__ xb, const ushort* __restrict__ Wb,
    const int* __restrict__ counts, const int* __restrict__ lists,
    const int* __restrict__ pbase, const int* __restrict__ ntiles,
    const int* __restrict__ desc, _Float16* __restrict__ delta)
{
    const int hw = blockIdx.x;
    const int l  = (hw & 7) * MAXTILES + (hw >> 3);
    const int ti = l >> 3;
    const int oi = l & 7;
    if (ti >= *ntiles) return;

    const int d     = desc[ti];
    const int e     = d >> 8;
    const int tile  = d & 255;
    const int n_e   = counts[e];
    const int tbase = tile << 7;
    const int o0    = oi * 256;
    const int prow0 = pbase[e] + tbase;

    __shared__ __align__(16) ushort As[128 * 64];   // 16 KiB
    __shared__ __align__(16) ushort Bs[256 * 64];   // 32 KiB

    const int tid  = threadIdx.x;
    const int lane = tid & 63;
    const int wid  = tid >> 6;
    const int wr   = wid >> 1, wc = wid & 1;

    const int ksrc = ((lane & 7) ^ (lane >> 3)) * 8;
    const ushort* srcA[4];
    #pragma unroll
    for (int g = 0; g < 4; ++g) {
        const int row  = g * 32 + wid * 8 + (lane >> 3);
        const int slot = min(tbase + row, n_e - 1);
        srcA[g] = xb + (size_t)lists[e * T_TOK + slot] * F_IN + ksrc;
    }
    const ushort* srcB = Wb + ((size_t)(e * F_OUT + o0 + wid * 8 + (lane >> 3))) * F_IN + ksrc;

    const int octx8 = ((lane >> 4) ^ (lane & 7)) * 8;
    const int ai    = (wr * 64  + (lane & 15)) * 64 + octx8;
    const int bi    = (wc * 128 + (lane & 15)) * 64 + octx8;

    f32x4 acc[4][8] = {};

    for (int ks = 0; ks < NKS; ++ks) {
        __syncthreads();
        #pragma unroll
        for (int g = 0; g < 4; ++g) {
            GLOAD16(srcA[g], As + (g * 32 + wid * 8) * 64);
            srcA[g] += 64;
        }
        #pragma unroll
        for (int g = 0; g < 8; ++g)
            GLOAD16(srcB + (size_t)g * 32 * F_IN, Bs + (g * 32 + wid * 8) * 64);
        srcB += 64;
        __syncthreads();

        short8 a[4][2], b[8][2];
        #pragma unroll
        for (int m = 0; m < 4; ++m) {
            a[m][0] = *(const short8*)(As + (ai + m * 1024));
            a[m][1] = *(const short8*)(As + ((ai + m * 1024) ^ 32));
        }
        #pragma unroll
        for (int n = 0; n < 8; ++n) {
            b[n][0] = *(const short8*)(Bs + (bi + n * 1024));
            b[n][1] = *(const short8*)(Bs + ((bi + n * 1024) ^ 32));
        }
        #pragma unroll
        for (int kk = 0; kk < 2; ++kk)
            #pragma unroll
            for (int m = 0; m < 4; ++m)
                #pragma unroll
                for (int n = 0; n < 8; ++n)
                    acc[m][n] = __builtin_amdgcn_mfma_f32_16x16x32_bf16(
                        a[m][kk], b[n][kk], acc[m][n], 0, 0, 0);
    }

    const int rl = (lane >> 4) * 4;
    const int cl = lane & 15;
    #pragma unroll
    for (int m = 0; m < 4; ++m)
        #pragma unroll
        for (int rr = 0; rr < 4; ++rr) {
            const int srow = wr * 64 + m * 16 + rl + rr;
            if (tbase + srow < n_e) {
                _Float16* drow = delta + (size_t)(prow0 + srow) * F_OUT + o0 + wc * 128 + cl;
                #pragma unroll
                for (int n = 0; n < 8; ++n)
                    drow[n * 16] = (_Float16)acc[m][n][rr];
            }
        }
}

// ---------------- combine: out[tok] = cf0*delta[p0] + cf1*delta[p1] ----------------
__global__ __launch_bounds__(256) void combine_kernel(
    const _Float16* __restrict__ delta, const int* __restrict__ pos,
    const float* __restrict__ coeffs, const int* __restrict__ pbase,
    float* __restrict__ out)
{
    const int tok = blockIdx.x;
    const int id0 = pos[tok * 2 + 0];
    const int id1 = pos[tok * 2 + 1];
    const float cf0 = coeffs[id0];
    const float cf1 = coeffs[id1];
    const int r0 = pbase[id0 >> 13] + (id0 & (T_TOK - 1));
    const int r1 = pbase[id1 >> 13] + (id1 & (T_TOK - 1));
    const int c  = threadIdx.x * 8;

    const half8 a = *(const half8*)(delta + (size_t)r0 * F_OUT + c);
    const half8 b = *(const half8*)(delta + (size_t)r1 * F_OUT + c);
    float4 o0, o1;
    o0.x = cf0 * (float)a[0] + cf1 * (float)b[0];
    o0.y = cf0 * (float)a[1] + cf1 * (float)b[1];
    o0.z = cf0 * (float)a[2] + cf1 * (float)b[2];
    o0.w = cf0 * (float)a[3] + cf1 * (float)b[3];
    o1.x = cf0 * (float)a[4] + cf1 * (float)b[4];
    o1.y = cf0 * (float)a[5] + cf1 * (float)b[5];
    o1.z = cf0 * (float)a[6] + cf1 * (float)b[6];
    o1.w = cf0 * (float)a[7] + cf1 * (float)b[7];
    float* op = out + (size_t)tok * F_OUT + c;
    *(float4*)(op)     = o0;
    *(float4*)(op + 4) = o1;
}

extern "C" void kernel_launch(void* const* d_in, const int* in_sizes, int n_in,
                              void* d_out, int out_size, void* d_ws, size_t ws_size,
                              hipStream_t stream) {
    const float* x      = (const float*)d_in[0];
    const float* protos = (const float*)d_in[1];
    const float* W      = (const float*)d_in[2];
    const int*   scal   = (const int*)d_in[3];
    float* out = (float*)d_out;

    char* ws = (char*)d_ws;
    int*      counts = (int*)(ws + 0);
    int*      pbase  = (int*)(ws + 64);
    int*      ntiles = (int*)(ws + 128);
    int*      desc   = (int*)(ws + 256);
    int*      pos    = (int*)(ws + 65536);
    int*      lists  = (int*)(ws + 262144);
    float*    coeffs = (float*)(ws + 524288);
    ushort*   xb     = (ushort*)(ws + (1ull << 20));
    ushort*   Wb     = (ushort*)(ws + (36ull << 20));
    _Float16* delta  = (_Float16*)(ws + (104ull << 20));

    hipMemsetAsync(counts, 0, N_EXP * sizeof(int), stream);

    route_cvt_kernel<<<ROUTE_BLOCKS + CVT_BLOCKS, 256, 0, stream>>>(
        x, protos, scal, xb, counts, lists, coeffs, pos, W, Wb);
    plan_kernel<<<1, 64, 0, stream>>>(counts, pbase, ntiles, desc);

    gemm_kernel<<<MAXTILES * 8, 256, 0, stream>>>(xb, Wb, counts, lists, pbase, ntiles, desc, delta);

    combine_kernel<<<T_TOK, 256, 0, stream>>>(delta, pos, coeffs, pbase, out);
}